// Round 8
// baseline (226.400 us; speedup 1.0000x reference)
//
#include <hip/hip_runtime.h>
#include <hip/hip_bf16.h>

typedef unsigned short u16;
typedef unsigned int u32;
typedef __bf16 bf16;
typedef bf16 bf16x8 __attribute__((ext_vector_type(8)));
typedef float f32x4 __attribute__((ext_vector_type(4)));

#define B_ 8
#define T_ 2048
#define C_ 768
#define MB 1048576ull
#define SCALE_Q 0.1803368867f   /* 0.125 * log2(e): folds 1/sqrt(64) and exp->exp2 */
#define NEG_INF (-__builtin_inff())

#define AS1 __attribute__((address_space(1)))
#define AS3 __attribute__((address_space(3)))

__device__ __forceinline__ void g2l16(const void* g, void* l) {
  __builtin_amdgcn_global_load_lds((AS1 const void*)g, (AS3 void*)l, 16, 0, 0);
}
__device__ __forceinline__ u16 bf2u(bf16 h) {
  union { bf16 h; u16 u; } x; x.h = h; return x.u;
}
#define MFMA16(A, B, C) __builtin_amdgcn_mfma_f32_16x16x32_bf16((A), (B), (C), 0, 0, 0)
#define SBAR() __builtin_amdgcn_sched_barrier(0)
#define WAITV4() asm volatile("s_waitcnt vmcnt(4)" ::: "memory")
#define WAITV0() asm volatile("s_waitcnt vmcnt(0)" ::: "memory")
#define BARRIER() do { SBAR(); __builtin_amdgcn_s_barrier(); SBAR(); } while (0)

// ---------------------------------------------------------------------------
// Kernel 1: pre-swizzled Wt image, DOUBLE-STEP packed (zero padding):
// 12 double-steps s2 (K=64 each), rows j=0..191 (0..63 = Wq cols, 64..127 =
// Wk, 128..191 = Wv), 128B pitch fully used:
// element (j, kk2) at byte (s2*192+j)*128 + ((2*kk2) ^ ((j&7)<<4)), kk2 in [0,64).
// Also zeroes the 1024 merge flags (block 0) for the fused attn merge.
// ---------------------------------------------------------------------------
__global__ __launch_bounds__(256) void prepw_kernel(const float* __restrict__ Wq,
                                                    const float* __restrict__ Wk,
                                                    const float* __restrict__ Wv,
                                                    u16* __restrict__ wt_img,
                                                    int* __restrict__ flags) {
  if (blockIdx.x == 0) {
    ((int4*)flags)[threadIdx.x] = make_int4(0, 0, 0, 0);   // 256*16B = 1024 ints
  }
  int tid = blockIdx.x * 256 + threadIdx.x;        // 3*768*64 = 147456 exactly
  int jj = tid & 63;
  int k  = (tid >> 6) % C_;
  int m  = tid / (64 * C_);
  const float* W = (m == 0) ? Wq : (m == 1 ? Wk : Wv);
  bf16 hv = (bf16)W[k * 64 + jj];
  int s2 = k >> 6, kk2 = k & 63, j = m * 64 + jj;
  int byteoff = (s2 * 192 + j) * 128 + ((2 * kk2) ^ ((j & 7) << 4));
  *(u16*)((char*)wt_img + byteoff) = bf2u(hv);
}

// ---------------------------------------------------------------------------
// Kernel 2: projections. Block = 1024 thr (16 waves, 4m x 4n), 64 rows x 192
// cols. 12 double-steps of K=64: per iter each wave does 6 MFMA (2 k-halves x
// 3 n-tiles). 3 LDS buffers (x 16KB as two 128B-pitch half-tiles + wt 24KB),
// 2-deep prefetch, per-wave counted vmcnt (waves 0-7: 3 loads/stage, 8-15: 2),
// 2 barriers/iter (3-buf rotation requires readers-done certification).
// ---------------------------------------------------------------------------
__global__ __launch_bounds__(1024) void proj_kernel(const float* __restrict__ x,
                                                    const u16* __restrict__ wt_img,
                                                    u16* __restrict__ q_ws,
                                                    u16* __restrict__ k_img,
                                                    u16* __restrict__ vt_img) {
  __shared__ __align__(16) char xt[3][16384];
  __shared__ __align__(16) char wt[3][24576];
  int tid = threadIdx.x, lane = tid & 63, w = tid >> 6;
  int wm = w & 3, wn = w >> 2;           // wm: m-tile (16 rows); wn: 48-col band
  int r0 = blockIdx.x * 64;
  int c = lane & 15, g = lane >> 4;

  f32x4 acc[3];
#pragma unroll
  for (int i = 0; i < 3; ++i) acc[i] = (f32x4){0.f, 0.f, 0.f, 0.f};

  // x staging: 1024 slots of 16B = two 8KB half-tiles (half = k-half of the
  // 64-wide double-step). slot xs: half = xs>>9, row = (xs>>3)&63, ch = xs&7.
  // LDS[half][row][ch] = x chunk (ch ^ (row&7)) of that half (swizzle via src).
  int xs = (tid < 512) ? (512 + tid) : (tid - 512);
  int xrow = (xs >> 3) & 63, xch = xs & 7, xhalf = xs >> 9;
  const float* srcx = x + (size_t)(r0 + xrow) * C_ + xhalf * 32 + ((xch ^ (xrow & 7)) << 2);

  auto STAGE = [&](int s, int bs) {
    const char* wsrc = (const char*)wt_img + s * 24576;
    g2l16(wsrc + tid * 16, wt[bs] + tid * 16);
    if (tid < 512) g2l16(wsrc + (1024 + tid) * 16, wt[bs] + (1024 + tid) * 16);
    g2l16(srcx + s * 64, xt[bs] + xs * 16);
  };

  STAGE(0, 0);
  STAGE(1, 1);

  int arow = wm * 16 + c;
  int ax = arow & 7;

  for (int s2 = 0; s2 < 12; ++s2) {
    int cur = s2 % 3;
    if (s2 < 10) {
      STAGE(s2 + 2, (s2 + 2) % 3);
      if (w < 8) asm volatile("s_waitcnt vmcnt(6)" ::: "memory");
      else       asm volatile("s_waitcnt vmcnt(4)" ::: "memory");
    } else if (s2 == 10) {
      if (w < 8) asm volatile("s_waitcnt vmcnt(3)" ::: "memory");
      else       asm volatile("s_waitcnt vmcnt(2)" ::: "memory");
    } else {
      asm volatile("s_waitcnt vmcnt(0)" ::: "memory");
    }
    BARRIER();                           // stage(s2) certified landed
    // A fragments: two k-halves from the two x half-tiles
    const char* x0 = xt[cur] + arow * 128;
    const char* x1 = x0 + 8192;
    f32x4 f0 = *(const f32x4*)(x0 + (((2 * g)     ^ ax) << 4));
    f32x4 f1 = *(const f32x4*)(x0 + (((2 * g + 1) ^ ax) << 4));
    f32x4 f2 = *(const f32x4*)(x1 + (((2 * g)     ^ ax) << 4));
    f32x4 f3 = *(const f32x4*)(x1 + (((2 * g + 1) ^ ax) << 4));
    bf16x8 af0, af1;
    af0[0] = (bf16)f0[0]; af0[1] = (bf16)f0[1]; af0[2] = (bf16)f0[2]; af0[3] = (bf16)f0[3];
    af0[4] = (bf16)f1[0]; af0[5] = (bf16)f1[1]; af0[6] = (bf16)f1[2]; af0[7] = (bf16)f1[3];
    af1[0] = (bf16)f2[0]; af1[1] = (bf16)f2[1]; af1[2] = (bf16)f2[2]; af1[3] = (bf16)f2[3];
    af1[4] = (bf16)f3[0]; af1[5] = (bf16)f3[1]; af1[6] = (bf16)f3[2]; af1[7] = (bf16)f3[3];
    const char* bb = wt[cur];
#pragma unroll
    for (int nt = 0; nt < 3; ++nt) {
      int brow = wn * 48 + nt * 16 + c;
      const char* br = bb + brow * 128;
      int bx = (brow & 7) << 4;
      bf16x8 b0 = *(const bf16x8*)(br + ((16 * g) ^ bx));
      bf16x8 b1 = *(const bf16x8*)(br + ((64 + 16 * g) ^ bx));
      acc[nt] = MFMA16(af0, b0, acc[nt]);
      acc[nt] = MFMA16(af1, b1, acc[nt]);
    }
    if (s2 < 11) {
      asm volatile("s_waitcnt lgkmcnt(0)" ::: "memory");
      BARRIER();                         // readers done -> buffer reusable
    }
  }

  // epilogue: D layout col = lane&15, row = (lane>>4)*4 + reg
#pragma unroll
  for (int nt = 0; nt < 3; ++nt) {
    int gc = wn * 48 + nt * 16;
    int m = gc >> 6;
    int h = (gc & 63) + c;
#pragma unroll
    for (int reg = 0; reg < 4; ++reg) {
      int r = r0 + wm * 16 + g * 4 + reg;   // token index
      float val = acc[nt][reg];
      int bb2 = r >> 11, rr = r & 2047, t = rr >> 6;
      if (m == 0) {
        q_ws[(size_t)r * 64 + h] = bf2u((bf16)(val * SCALE_Q));
      } else if (m == 1) {
        int ntk = (rr >> 4) & 3, ck = rr & 15;
        int jp = h >> 5, gg = (h >> 3) & 3, jj = h & 7;
        k_img[((size_t)(bb2 * 32 + t)) * 4096 + ntk * 1024 + jp * 512 + gg * 128 + ck * 8 + jj] = bf2u((bf16)val);
      } else {
        int ht = h >> 4, cv = h & 15;
        int jpv = (rr >> 5) & 1, gv = (rr >> 3) & 3, jv = rr & 7;
        vt_img[((size_t)(bb2 * 32 + t)) * 4096 + ht * 1024 + jpv * 512 + gv * 128 + cv * 8 + jv] = bf2u((bf16)val);
      }
    }
  }
}

// ---------------------------------------------------------------------------
// Kernel 3: causal flash attention, split-KV, block-cooperative LDS staging,
// FUSED merge: per (b,qt) atomic ticket; the last-arriving chunk wave merges
// all partials and writes out (release/acquire via __threadfence + atomicAdd).
// Block = 4 waves = q-tiles {4qb..4qb+3}, same KV chunk of <=4 tiles of 64.
// ---------------------------------------------------------------------------
__device__ __forceinline__ void tile_body(int tt, const char* kb, const char* vb,
                                          int nkt, int q0,
                                          const bf16x8& qb0, const bf16x8& qb1,
                                          int lane, int c, int g, char* pw,
                                          f32x4 (&accO)[4], float& mrun, float& lrun) {
  int lb = lane * 16;
  bf16x8 kf[4][2], vf[4][2];
#pragma unroll
  for (int nt = 0; nt < 4; ++nt)
#pragma unroll
    for (int jp = 0; jp < 2; ++jp)
      kf[nt][jp] = *(const bf16x8*)(kb + nt * 2048 + jp * 1024 + lb);
#pragma unroll
  for (int ht = 0; ht < 4; ++ht)
#pragma unroll
    for (int jp = 0; jp < 2; ++jp)
      vf[ht][jp] = *(const bf16x8*)(vb + ht * 2048 + jp * 1024 + lb);
  // S^T[kpos][q] = K . Q^T   (rows = kpos, cols = q = lane&15)
  f32x4 st[4];
#pragma unroll
  for (int nt = 0; nt < 4; ++nt) {
    f32x4 z = (f32x4){0.f, 0.f, 0.f, 0.f};
    z = MFMA16(kf[nt][0], qb0, z);
    st[nt] = MFMA16(kf[nt][1], qb1, z);
  }
  if (tt == nkt - 1) {   // diagonal tile: mask kpos > q
    int qg = q0 + c, kb2 = tt * 64 + g * 4;
#pragma unroll
    for (int nt = 0; nt < 4; ++nt)
#pragma unroll
      for (int reg = 0; reg < 4; ++reg)
        if (kb2 + nt * 16 + reg > qg) st[nt][reg] = NEG_INF;
  }
  // lane-local softmax over 16 held kpos + cross-group (xor16, xor32)
  float smax = st[0][0];
#pragma unroll
  for (int nt = 0; nt < 4; ++nt)
#pragma unroll
    for (int reg = 0; reg < 4; ++reg) smax = fmaxf(smax, st[nt][reg]);
  smax = fmaxf(smax, __shfl_xor(smax, 16));
  smax = fmaxf(smax, __shfl_xor(smax, 32));
  float mnew = fmaxf(mrun, smax);
  float sf = exp2f(mrun - mnew);
  float rsum = 0.f;
  u32 pk[4][2];
#pragma unroll
  for (int nt = 0; nt < 4; ++nt)
#pragma unroll
    for (int jp = 0; jp < 2; ++jp) {
      float p0 = exp2f(st[nt][2 * jp] - mnew);
      float p1 = exp2f(st[nt][2 * jp + 1] - mnew);
      rsum += p0 + p1;
      pk[nt][jp] = (u32)bf2u((bf16)p0) | ((u32)bf2u((bf16)p1) << 16);
    }
  rsum += __shfl_xor(rsum, 16);
  rsum += __shfl_xor(rsum, 32);
  lrun = lrun * sf + rsum;
  mrun = mnew;
#pragma unroll
  for (int ht = 0; ht < 4; ++ht) accO[ht] *= sf;
  // P (q-row c, 64 kpos) -> wave-private swizzled LDS row, packed b32 writes
  int swz = (c & 7) << 4;
#pragma unroll
  for (int nt = 0; nt < 4; ++nt)
#pragma unroll
    for (int jp = 0; jp < 2; ++jp) {
      int kpos = nt * 16 + g * 4 + 2 * jp;
      *(u32*)(pw + ((2 * kpos) ^ swz)) = pk[nt][jp];
    }
  // P^T as B-operand: col = q = c, k = kpos (8 consecutive)
  bf16x8 pf0 = *(const bf16x8*)(pw + ((16 * g) ^ swz));
  bf16x8 pf1 = *(const bf16x8*)(pw + ((64 + 16 * g) ^ swz));
#pragma unroll
  for (int ht = 0; ht < 4; ++ht) {
    accO[ht] = MFMA16(vf[ht][0], pf0, accO[ht]);
    accO[ht] = MFMA16(vf[ht][1], pf1, accO[ht]);
  }
}

__global__ __launch_bounds__(256) void attn_kernel(const u16* __restrict__ q_ws,
                                                   const u16* __restrict__ k_img,
                                                   const u16* __restrict__ vt_img,
                                                   float* __restrict__ po,
                                                   float* __restrict__ ml,
                                                   int* __restrict__ flags,
                                                   float* __restrict__ out) {
  __shared__ __align__(16) char sK[2][8192];
  __shared__ __align__(16) char sV[2][8192];
  __shared__ __align__(16) char sP[4 * 2048];
  int tid = threadIdx.x, lane = tid & 63, w = tid >> 6;
  int bid = blockIdx.x;
  int b = bid & 7;                       // batch -> XCD
  int v = bid >> 3;                      // [0, 144)
  int p, lo;
  if (v < 4)        { p = 0; lo = 0; }
  else if (v < 12)  { p = 1; lo = 4; }
  else if (v < 24)  { p = 2; lo = 12; }
  else if (v < 40)  { p = 3; lo = 24; }
  else if (v < 60)  { p = 4; lo = 40; }
  else if (v < 84)  { p = 5; lo = 60; }
  else if (v < 112) { p = 6; lo = 84; }
  else              { p = 7; lo = 112; }
  int local = v - lo;
  int qb = 4 * p + (local & 3);          // 64-row band index [0,32)
  int ci = local >> 2;                   // chunk index [0, (qb>>2)]
  int nkt = qb + 1;
  int t0 = 4 * ci;
  int n = nkt - t0; if (n > 4) n = 4;
  int m = qb >> 2;                       // band; nc = m+1 chunks
  int nc = m + 1;
  int qt = 4 * qb + w;
  int q0 = qt * 16;
  int c = lane & 15, g = lane >> 4;

  const u16* qb_p = q_ws + ((size_t)b * T_ + q0 + c) * 64 + 8 * g;
  bf16x8 qb0 = *(const bf16x8*)qb_p;
  bf16x8 qb1 = *(const bf16x8*)(qb_p + 32);

  auto STAGE = [&](int t, int bs) {
    const u16* ks = k_img + ((size_t)(b * 32 + t0 + t)) * 4096;
    const u16* vs = vt_img + ((size_t)(b * 32 + t0 + t)) * 4096;
    g2l16(ks + tid * 8,        sK[bs] + tid * 16);
    g2l16(ks + 2048 + tid * 8, sK[bs] + 4096 + tid * 16);
    g2l16(vs + tid * 8,        sV[bs] + tid * 16);
    g2l16(vs + 2048 + tid * 8, sV[bs] + 4096 + tid * 16);
  };

  f32x4 accO[4];
#pragma unroll
  for (int i = 0; i < 4; ++i) accO[i] = (f32x4){0.f, 0.f, 0.f, 0.f};
  float mrun = NEG_INF, lrun = 0.f;
  char* pw = sP + w * 2048 + c * 128;

  STAGE(0, 0);
  if (n > 1) STAGE(1, 1);
  if (n > 1) WAITV4(); else WAITV0();
  BARRIER();
  tile_body(t0 + 0, sK[0], sV[0], nkt, q0, qb0, qb1, lane, c, g, pw, accO, mrun, lrun);
  if (n > 1) {
    BARRIER();
    if (n > 2) STAGE(2, 0);
    if (n > 2) WAITV4(); else WAITV0();
    BARRIER();
    tile_body(t0 + 1, sK[1], sV[1], nkt, q0, qb0, qb1, lane, c, g, pw, accO, mrun, lrun);
  }
  if (n > 2) {
    BARRIER();
    if (n > 3) STAGE(3, 1);
    if (n > 3) WAITV4(); else WAITV0();
    BARRIER();
    tile_body(t0 + 2, sK[0], sV[0], nkt, q0, qb0, qb1, lane, c, g, pw, accO, mrun, lrun);
  }
  if (n > 3) {
    WAITV0();
    BARRIER();
    tile_body(t0 + 3, sK[1], sV[1], nkt, q0, qb0, qb1, lane, c, g, pw, accO, mrun, lrun);
  }

  if (nc == 1) {
    // single chunk (qb < 4): normalize, write out (lane holds out col q=c)
    float rl = 1.f / lrun;
    float* ob = out + ((size_t)b * T_ + q0 + c) * 64;
#pragma unroll
    for (int ht = 0; ht < 4; ++ht)
#pragma unroll
      for (int reg = 0; reg < 4; ++reg)
        ob[ht * 16 + g * 4 + reg] = accO[ht][reg] * rl;
  } else {
    // write partial slot
    int sb = b * 576 + 8 * m * (m + 1) + (qt & 15);
    int slot = sb + 16 * ci;
    float* pb = po + (size_t)slot * 1024;   // [64 h][16 q] f32
#pragma unroll
    for (int ht = 0; ht < 4; ++ht)
#pragma unroll
      for (int reg = 0; reg < 4; ++reg)
        pb[(ht * 16 + g * 4 + reg) * 16 + c] = accO[ht][reg];
    if (g == 0) {
      float2 v2; v2.x = mrun; v2.y = lrun;
      *(float2*)(ml + (size_t)slot * 32 + c * 2) = v2;
    }
    __threadfence();                       // release: po/ml visible device-wide
    int ticket = 0;
    if (lane == 0) ticket = atomicAdd(&flags[b * 128 + qt], 1);
    ticket = __shfl(ticket, 0);
    if (ticket == nc - 1) {
      __threadfence();                     // acquire
      // this wave merges all nc chunks for (b,qt). lane (c,g): q=c, h=g*16+i.
      float M = NEG_INF;
#pragma unroll
      for (int c2 = 0; c2 < 8; ++c2)
        if (c2 < nc) M = fmaxf(M, ml[(size_t)(sb + 16 * c2) * 32 + c * 2]);
      float wgt[8];
      float L = 0.f;
#pragma unroll
      for (int c2 = 0; c2 < 8; ++c2) {
        if (c2 < nc) {
          float2 mlv = *(const float2*)(ml + (size_t)(sb + 16 * c2) * 32 + c * 2);
          wgt[c2] = exp2f(mlv.x - M);
          L += wgt[c2] * mlv.y;
        } else {
          wgt[c2] = 0.f;
        }
      }
      float rl = 1.f / L;
      float* ob = out + ((size_t)b * T_ + q0 + c) * 64 + g * 16;
      f32x4 ov;
#pragma unroll
      for (int i = 0; i < 16; ++i) {
        float s = 0.f;
#pragma unroll
        for (int c2 = 0; c2 < 8; ++c2)
          if (c2 < nc)
            s += wgt[c2] * po[(size_t)(sb + 16 * c2) * 1024 + (g * 16 + i) * 16 + c];
        ov[i & 3] = s * rl;
        if ((i & 3) == 3) *(f32x4*)(ob + (i - 3)) = ov;
      }
    }
  }
}

// ---------------------------------------------------------------------------
extern "C" void kernel_launch(void* const* d_in, const int* in_sizes, int n_in,
                              void* d_out, int out_size, void* d_ws, size_t ws_size,
                              hipStream_t stream) {
  const float* x  = (const float*)d_in[0];
  const float* Wk = (const float*)d_in[1];
  const float* Wq = (const float*)d_in[2];
  const float* Wv = (const float*)d_in[3];
  char* ws = (char*)d_ws;
  u16* q_ws   = (u16*)(ws);                //  0MB: [16384][64] bf16 (q * 0.125*log2e)
  u16* k_img  = (u16*)(ws + 2 * MB);       //  2MB: [8][32][4096] u16 tile image
  u16* vt_img = (u16*)(ws + 4 * MB);       //  4MB: [8][32][4096] u16 tile image
  u16* wt_img = (u16*)(ws + 6 * MB);       //  6MB: 295KB packed swizzled weights
  float* po   = (float*)(ws + 8 * MB);     //  8MB: 4608 slots x [64][16] f32 = 18.9MB
  float* ml   = (float*)(ws + 28 * MB);    // 28MB: 4608 x [16][2] f32 = 590KB
  int* flags  = (int*)(ws + 29 * MB);      // 29MB: 1024 ints (merge tickets)
  float* out = (float*)d_out;

  prepw_kernel<<<576, 256, 0, stream>>>(Wq, Wk, Wv, wt_img, flags);
  proj_kernel<<<256, 1024, 0, stream>>>(x, wt_img, q_ws, k_img, vt_img);
  attn_kernel<<<1152, 256, 0, stream>>>(q_ws, k_img, vt_img, po, ml, flags, out);
}

// Round 9
// 50.338 us; speedup vs baseline: 4.4976x; 4.4976x over previous
//
#include <hip/hip_runtime.h>
#include <hip/hip_bf16.h>

typedef unsigned short u16;
typedef unsigned int u32;
typedef __bf16 bf16;
typedef bf16 bf16x8 __attribute__((ext_vector_type(8)));
typedef float f32x4 __attribute__((ext_vector_type(4)));

#define B_ 8
#define T_ 2048
#define C_ 768
#define MB 1048576ull
#define SCALE_Q 0.1803368867f   /* 0.125 * log2(e): folds 1/sqrt(64) and exp->exp2 */
#define NEG_INF (-__builtin_inff())

#define AS1 __attribute__((address_space(1)))
#define AS3 __attribute__((address_space(3)))

__device__ __forceinline__ void g2l16(const void* g, void* l) {
  __builtin_amdgcn_global_load_lds((AS1 const void*)g, (AS3 void*)l, 16, 0, 0);
}
__device__ __forceinline__ u16 bf2u(bf16 h) {
  union { bf16 h; u16 u; } x; x.h = h; return x.u;
}
#define MFMA16(A, B, C) __builtin_amdgcn_mfma_f32_16x16x32_bf16((A), (B), (C), 0, 0, 0)
#define SBAR() __builtin_amdgcn_sched_barrier(0)
#define WAITV4() asm volatile("s_waitcnt vmcnt(4)" ::: "memory")
#define WAITV0() asm volatile("s_waitcnt vmcnt(0)" ::: "memory")
#define BARRIER() do { SBAR(); __builtin_amdgcn_s_barrier(); SBAR(); } while (0)

// ---------------------------------------------------------------------------
// Kernel 1: pre-swizzled Wt image, DOUBLE-STEP packed (zero padding):
// 12 double-steps s2 (K=64 each), rows j=0..191 (0..63 = Wq cols, 64..127 =
// Wk, 128..191 = Wv), 128B pitch fully used:
// element (j, kk2) at byte (s2*192+j)*128 + ((2*kk2) ^ ((j&7)<<4)), kk2 in [0,64).
// ---------------------------------------------------------------------------
__global__ __launch_bounds__(256) void prepw_kernel(const float* __restrict__ Wq,
                                                    const float* __restrict__ Wk,
                                                    const float* __restrict__ Wv,
                                                    u16* __restrict__ wt_img) {
  int tid = blockIdx.x * 256 + threadIdx.x;        // 3*768*64 = 147456 exactly
  int jj = tid & 63;
  int k  = (tid >> 6) % C_;
  int m  = tid / (64 * C_);
  const float* W = (m == 0) ? Wq : (m == 1 ? Wk : Wv);
  bf16 hv = (bf16)W[k * 64 + jj];
  int s2 = k >> 6, kk2 = k & 63, j = m * 64 + jj;
  int byteoff = (s2 * 192 + j) * 128 + ((2 * kk2) ^ ((j & 7) << 4));
  *(u16*)((char*)wt_img + byteoff) = bf2u(hv);
}

// ---------------------------------------------------------------------------
// Kernel 2: projections. Block = 1024 thr (16 waves, 4m x 4n), 64 rows x 192
// cols. 12 double-steps of K=64: per iter each wave does 6 MFMA (2 k-halves x
// 3 n-tiles). 3 LDS buffers (x 16KB as two 128B-pitch half-tiles + wt 24KB),
// 2-deep prefetch, per-wave counted vmcnt (waves 0-7: 3 loads/stage, 8-15: 2),
// 2 barriers/iter. (Round-8 version — proven correct, now isolated.)
// ---------------------------------------------------------------------------
__global__ __launch_bounds__(1024) void proj_kernel(const float* __restrict__ x,
                                                    const u16* __restrict__ wt_img,
                                                    u16* __restrict__ q_ws,
                                                    u16* __restrict__ k_img,
                                                    u16* __restrict__ vt_img) {
  __shared__ __align__(16) char xt[3][16384];
  __shared__ __align__(16) char wt[3][24576];
  int tid = threadIdx.x, lane = tid & 63, w = tid >> 6;
  int wm = w & 3, wn = w >> 2;           // wm: m-tile (16 rows); wn: 48-col band
  int r0 = blockIdx.x * 64;
  int c = lane & 15, g = lane >> 4;

  f32x4 acc[3];
#pragma unroll
  for (int i = 0; i < 3; ++i) acc[i] = (f32x4){0.f, 0.f, 0.f, 0.f};

  // x staging: 1024 slots of 16B = two 8KB half-tiles (half = k-half of the
  // 64-wide double-step). slot xs: half = xs>>9, row = (xs>>3)&63, ch = xs&7.
  // LDS[half][row][ch] = x chunk (ch ^ (row&7)) of that half (swizzle via src).
  int xs = (tid < 512) ? (512 + tid) : (tid - 512);
  int xrow = (xs >> 3) & 63, xch = xs & 7, xhalf = xs >> 9;
  const float* srcx = x + (size_t)(r0 + xrow) * C_ + xhalf * 32 + ((xch ^ (xrow & 7)) << 2);

  auto STAGE = [&](int s, int bs) {
    const char* wsrc = (const char*)wt_img + s * 24576;
    g2l16(wsrc + tid * 16, wt[bs] + tid * 16);
    if (tid < 512) g2l16(wsrc + (1024 + tid) * 16, wt[bs] + (1024 + tid) * 16);
    g2l16(srcx + s * 64, xt[bs] + xs * 16);
  };

  STAGE(0, 0);
  STAGE(1, 1);

  int arow = wm * 16 + c;
  int ax = arow & 7;

  for (int s2 = 0; s2 < 12; ++s2) {
    int cur = s2 % 3;
    if (s2 < 10) {
      STAGE(s2 + 2, (s2 + 2) % 3);
      if (w < 8) asm volatile("s_waitcnt vmcnt(6)" ::: "memory");
      else       asm volatile("s_waitcnt vmcnt(4)" ::: "memory");
    } else if (s2 == 10) {
      if (w < 8) asm volatile("s_waitcnt vmcnt(3)" ::: "memory");
      else       asm volatile("s_waitcnt vmcnt(2)" ::: "memory");
    } else {
      asm volatile("s_waitcnt vmcnt(0)" ::: "memory");
    }
    BARRIER();                           // stage(s2) certified landed
    // A fragments: two k-halves from the two x half-tiles
    const char* x0 = xt[cur] + arow * 128;
    const char* x1 = x0 + 8192;
    f32x4 f0 = *(const f32x4*)(x0 + (((2 * g)     ^ ax) << 4));
    f32x4 f1 = *(const f32x4*)(x0 + (((2 * g + 1) ^ ax) << 4));
    f32x4 f2 = *(const f32x4*)(x1 + (((2 * g)     ^ ax) << 4));
    f32x4 f3 = *(const f32x4*)(x1 + (((2 * g + 1) ^ ax) << 4));
    bf16x8 af0, af1;
    af0[0] = (bf16)f0[0]; af0[1] = (bf16)f0[1]; af0[2] = (bf16)f0[2]; af0[3] = (bf16)f0[3];
    af0[4] = (bf16)f1[0]; af0[5] = (bf16)f1[1]; af0[6] = (bf16)f1[2]; af0[7] = (bf16)f1[3];
    af1[0] = (bf16)f2[0]; af1[1] = (bf16)f2[1]; af1[2] = (bf16)f2[2]; af1[3] = (bf16)f2[3];
    af1[4] = (bf16)f3[0]; af1[5] = (bf16)f3[1]; af1[6] = (bf16)f3[2]; af1[7] = (bf16)f3[3];
    const char* bb = wt[cur];
#pragma unroll
    for (int nt = 0; nt < 3; ++nt) {
      int brow = wn * 48 + nt * 16 + c;
      const char* br = bb + brow * 128;
      int bx = (brow & 7) << 4;
      bf16x8 b0 = *(const bf16x8*)(br + ((16 * g) ^ bx));
      bf16x8 b1 = *(const bf16x8*)(br + ((64 + 16 * g) ^ bx));
      acc[nt] = MFMA16(af0, b0, acc[nt]);
      acc[nt] = MFMA16(af1, b1, acc[nt]);
    }
    if (s2 < 11) {
      asm volatile("s_waitcnt lgkmcnt(0)" ::: "memory");
      BARRIER();                         // readers done -> buffer reusable
    }
  }

  // epilogue: D layout col = lane&15, row = (lane>>4)*4 + reg
#pragma unroll
  for (int nt = 0; nt < 3; ++nt) {
    int gc = wn * 48 + nt * 16;
    int m = gc >> 6;
    int h = (gc & 63) + c;
#pragma unroll
    for (int reg = 0; reg < 4; ++reg) {
      int r = r0 + wm * 16 + g * 4 + reg;   // token index
      float val = acc[nt][reg];
      int bb2 = r >> 11, rr = r & 2047, t = rr >> 6;
      if (m == 0) {
        q_ws[(size_t)r * 64 + h] = bf2u((bf16)(val * SCALE_Q));
      } else if (m == 1) {
        int ntk = (rr >> 4) & 3, ck = rr & 15;
        int jp = h >> 5, gg = (h >> 3) & 3, jj = h & 7;
        k_img[((size_t)(bb2 * 32 + t)) * 4096 + ntk * 1024 + jp * 512 + gg * 128 + ck * 8 + jj] = bf2u((bf16)val);
      } else {
        int ht = h >> 4, cv = h & 15;
        int jpv = (rr >> 5) & 1, gv = (rr >> 3) & 3, jv = rr & 7;
        vt_img[((size_t)(bb2 * 32 + t)) * 4096 + ht * 1024 + jpv * 512 + gv * 128 + cv * 8 + jv] = bf2u((bf16)val);
      }
    }
  }
}

// ---------------------------------------------------------------------------
// Kernel 3: causal flash attention, split-KV, block-cooperative LDS staging.
// (Round-7 version, fused merge REVERTED — device-scope fences per wave
// caused an L2 writeback storm: FETCH 3.2->12.5 GB. Kernel boundary provides
// the cross-XCD visibility for free.)
// ---------------------------------------------------------------------------
__device__ __forceinline__ void tile_body(int tt, const char* kb, const char* vb,
                                          int nkt, int q0,
                                          const bf16x8& qb0, const bf16x8& qb1,
                                          int lane, int c, int g, char* pw,
                                          f32x4 (&accO)[4], float& mrun, float& lrun) {
  int lb = lane * 16;
  bf16x8 kf[4][2], vf[4][2];
#pragma unroll
  for (int nt = 0; nt < 4; ++nt)
#pragma unroll
    for (int jp = 0; jp < 2; ++jp)
      kf[nt][jp] = *(const bf16x8*)(kb + nt * 2048 + jp * 1024 + lb);
#pragma unroll
  for (int ht = 0; ht < 4; ++ht)
#pragma unroll
    for (int jp = 0; jp < 2; ++jp)
      vf[ht][jp] = *(const bf16x8*)(vb + ht * 2048 + jp * 1024 + lb);
  // S^T[kpos][q] = K . Q^T   (rows = kpos, cols = q = lane&15)
  f32x4 st[4];
#pragma unroll
  for (int nt = 0; nt < 4; ++nt) {
    f32x4 z = (f32x4){0.f, 0.f, 0.f, 0.f};
    z = MFMA16(kf[nt][0], qb0, z);
    st[nt] = MFMA16(kf[nt][1], qb1, z);
  }
  if (tt == nkt - 1) {   // diagonal tile: mask kpos > q
    int qg = q0 + c, kb2 = tt * 64 + g * 4;
#pragma unroll
    for (int nt = 0; nt < 4; ++nt)
#pragma unroll
      for (int reg = 0; reg < 4; ++reg)
        if (kb2 + nt * 16 + reg > qg) st[nt][reg] = NEG_INF;
  }
  // lane-local softmax over 16 held kpos + cross-group (xor16, xor32)
  float smax = st[0][0];
#pragma unroll
  for (int nt = 0; nt < 4; ++nt)
#pragma unroll
    for (int reg = 0; reg < 4; ++reg) smax = fmaxf(smax, st[nt][reg]);
  smax = fmaxf(smax, __shfl_xor(smax, 16));
  smax = fmaxf(smax, __shfl_xor(smax, 32));
  float mnew = fmaxf(mrun, smax);
  float sf = exp2f(mrun - mnew);
  float rsum = 0.f;
  u32 pk[4][2];
#pragma unroll
  for (int nt = 0; nt < 4; ++nt)
#pragma unroll
    for (int jp = 0; jp < 2; ++jp) {
      float p0 = exp2f(st[nt][2 * jp] - mnew);
      float p1 = exp2f(st[nt][2 * jp + 1] - mnew);
      rsum += p0 + p1;
      pk[nt][jp] = (u32)bf2u((bf16)p0) | ((u32)bf2u((bf16)p1) << 16);
    }
  rsum += __shfl_xor(rsum, 16);
  rsum += __shfl_xor(rsum, 32);
  lrun = lrun * sf + rsum;
  mrun = mnew;
#pragma unroll
  for (int ht = 0; ht < 4; ++ht) accO[ht] *= sf;
  // P (q-row c, 64 kpos) -> wave-private swizzled LDS row, packed b32 writes
  int swz = (c & 7) << 4;
#pragma unroll
  for (int nt = 0; nt < 4; ++nt)
#pragma unroll
    for (int jp = 0; jp < 2; ++jp) {
      int kpos = nt * 16 + g * 4 + 2 * jp;
      *(u32*)(pw + ((2 * kpos) ^ swz)) = pk[nt][jp];
    }
  // P^T as B-operand: col = q = c, k = kpos (8 consecutive)
  bf16x8 pf0 = *(const bf16x8*)(pw + ((16 * g) ^ swz));
  bf16x8 pf1 = *(const bf16x8*)(pw + ((64 + 16 * g) ^ swz));
#pragma unroll
  for (int ht = 0; ht < 4; ++ht) {
    accO[ht] = MFMA16(vf[ht][0], pf0, accO[ht]);
    accO[ht] = MFMA16(vf[ht][1], pf1, accO[ht]);
  }
}

__global__ __launch_bounds__(256) void attn_kernel(const u16* __restrict__ q_ws,
                                                   const u16* __restrict__ k_img,
                                                   const u16* __restrict__ vt_img,
                                                   float* __restrict__ po,
                                                   float* __restrict__ ml,
                                                   float* __restrict__ out) {
  __shared__ __align__(16) char sK[2][8192];
  __shared__ __align__(16) char sV[2][8192];
  __shared__ __align__(16) char sP[4 * 2048];
  int tid = threadIdx.x, lane = tid & 63, w = tid >> 6;
  int bid = blockIdx.x;
  int b = bid & 7;                       // batch -> XCD
  int v = bid >> 3;                      // [0, 144)
  int p, lo;
  if (v < 4)        { p = 0; lo = 0; }
  else if (v < 12)  { p = 1; lo = 4; }
  else if (v < 24)  { p = 2; lo = 12; }
  else if (v < 40)  { p = 3; lo = 24; }
  else if (v < 60)  { p = 4; lo = 40; }
  else if (v < 84)  { p = 5; lo = 60; }
  else if (v < 112) { p = 6; lo = 84; }
  else              { p = 7; lo = 112; }
  int local = v - lo;
  int qb = 4 * p + (local & 3);          // 64-row band index [0,32)
  int ci = local >> 2;                   // chunk index [0, (qb>>2)]
  int nkt = qb + 1;
  int t0 = 4 * ci;
  int n = nkt - t0; if (n > 4) n = 4;
  int m = qb >> 2;                       // band (matches qt>>4 for all 4 waves)
  int nc = m + 1;
  int qt = 4 * qb + w;
  int q0 = qt * 16;
  int c = lane & 15, g = lane >> 4;

  const u16* qb_p = q_ws + ((size_t)b * T_ + q0 + c) * 64 + 8 * g;
  bf16x8 qb0 = *(const bf16x8*)qb_p;
  bf16x8 qb1 = *(const bf16x8*)(qb_p + 32);

  auto STAGE = [&](int t, int bs) {
    const u16* ks = k_img + ((size_t)(b * 32 + t0 + t)) * 4096;
    const u16* vs = vt_img + ((size_t)(b * 32 + t0 + t)) * 4096;
    g2l16(ks + tid * 8,        sK[bs] + tid * 16);
    g2l16(ks + 2048 + tid * 8, sK[bs] + 4096 + tid * 16);
    g2l16(vs + tid * 8,        sV[bs] + tid * 16);
    g2l16(vs + 2048 + tid * 8, sV[bs] + 4096 + tid * 16);
  };

  f32x4 accO[4];
#pragma unroll
  for (int i = 0; i < 4; ++i) accO[i] = (f32x4){0.f, 0.f, 0.f, 0.f};
  float mrun = NEG_INF, lrun = 0.f;
  char* pw = sP + w * 2048 + c * 128;

  STAGE(0, 0);
  if (n > 1) STAGE(1, 1);
  if (n > 1) WAITV4(); else WAITV0();
  BARRIER();                                  // certify stage 0 (all waves)
  tile_body(t0 + 0, sK[0], sV[0], nkt, q0, qb0, qb1, lane, c, g, pw, accO, mrun, lrun);
  if (n > 1) {
    BARRIER();                                // readers of buf0 done
    if (n > 2) STAGE(2, 0);
    if (n > 2) WAITV4(); else WAITV0();
    BARRIER();                                // certify stage 1
    tile_body(t0 + 1, sK[1], sV[1], nkt, q0, qb0, qb1, lane, c, g, pw, accO, mrun, lrun);
  }
  if (n > 2) {
    BARRIER();                                // readers of buf1 done
    if (n > 3) STAGE(3, 1);
    if (n > 3) WAITV4(); else WAITV0();
    BARRIER();                                // certify stage 2
    tile_body(t0 + 2, sK[0], sV[0], nkt, q0, qb0, qb1, lane, c, g, pw, accO, mrun, lrun);
  }
  if (n > 3) {
    WAITV0();                                 // my stage-3 chunks landed
    BARRIER();                                // everyone's landed
    tile_body(t0 + 3, sK[1], sV[1], nkt, q0, qb0, qb1, lane, c, g, pw, accO, mrun, lrun);
  }

  if (nc == 1) {
    // single chunk (qb < 4): normalize, write out (lane holds out col q=c)
    float rl = 1.f / lrun;
    float* ob = out + ((size_t)b * T_ + q0 + c) * 64;
#pragma unroll
    for (int ht = 0; ht < 4; ++ht)
#pragma unroll
      for (int reg = 0; reg < 4; ++reg)
        ob[ht * 16 + g * 4 + reg] = accO[ht][reg] * rl;
  } else {
    int u = 8 * m * (m + 1) + ci * 16 + (qt & 15);
    int slot = b * 576 + u;
    float* pb = po + (size_t)slot * 1024;   // [64 h][16 q] f32
#pragma unroll
    for (int ht = 0; ht < 4; ++ht)
#pragma unroll
      for (int reg = 0; reg < 4; ++reg)
        pb[(ht * 16 + g * 4 + reg) * 16 + c] = accO[ht][reg];
    if (g == 0) {
      float2 v2; v2.x = mrun; v2.y = lrun;
      *(float2*)(ml + (size_t)slot * 32 + c * 2) = v2;
    }
  }
}

// ---------------------------------------------------------------------------
// Kernel 4: merge split-KV partials for qt in [16,128). Block = one (b,qt).
// Grid MUST be 112*8 = 896. Band m = qt>>4, nc = m+1 chunks at stride 16.
// ---------------------------------------------------------------------------
__global__ __launch_bounds__(256) void merge_kernel(const float* __restrict__ po,
                                                    const float* __restrict__ ml,
                                                    float* __restrict__ out) {
  int bid = blockIdx.x;                 // 896 = 112 * 8
  int b = bid & 7, qi = bid >> 3;
  int qt = 16 + qi;                     // [16, 128)
  int m = qt >> 4;                      // 1..7
  int nc = m + 1;
  int sbase = b * 576 + 8 * m * (m + 1) + (qt & 15);
  int q = threadIdx.x & 15, hq = threadIdx.x >> 4;   // hq in [0,16): h0 = hq*4

  float M = NEG_INF;
  for (int ci = 0; ci < nc; ++ci) {
    float mv = ml[(size_t)(sbase + 16 * ci) * 32 + q * 2];
    M = fmaxf(M, mv);
  }
  float L = 0.f;
  f32x4 acc = (f32x4){0.f, 0.f, 0.f, 0.f};
  for (int ci = 0; ci < nc; ++ci) {
    int sl = sbase + 16 * ci;
    float2 mlv = *(const float2*)(ml + (size_t)sl * 32 + q * 2);
    float wgt = exp2f(mlv.x - M);
    L += wgt * mlv.y;
    const float* pb = po + (size_t)sl * 1024 + hq * 64 + q;
    acc[0] += wgt * pb[0];
    acc[1] += wgt * pb[16];
    acc[2] += wgt * pb[32];
    acc[3] += wgt * pb[48];
  }
  float rl = 1.f / L;
  f32x4 res = acc * rl;
  *(f32x4*)(out + ((size_t)b * T_ + (size_t)qt * 16 + q) * 64 + hq * 4) = res;
}

// ---------------------------------------------------------------------------
extern "C" void kernel_launch(void* const* d_in, const int* in_sizes, int n_in,
                              void* d_out, int out_size, void* d_ws, size_t ws_size,
                              hipStream_t stream) {
  const float* x  = (const float*)d_in[0];
  const float* Wk = (const float*)d_in[1];
  const float* Wq = (const float*)d_in[2];
  const float* Wv = (const float*)d_in[3];
  char* ws = (char*)d_ws;
  u16* q_ws   = (u16*)(ws);                //  0MB: [16384][64] bf16 (q * 0.125*log2e)
  u16* k_img  = (u16*)(ws + 2 * MB);       //  2MB: [8][32][4096] u16 tile image
  u16* vt_img = (u16*)(ws + 4 * MB);       //  4MB: [8][32][4096] u16 tile image
  u16* wt_img = (u16*)(ws + 6 * MB);       //  6MB: 295KB packed swizzled weights
  float* po   = (float*)(ws + 8 * MB);     //  8MB: 4608 slots x [64][16] f32 = 18.9MB
  float* ml   = (float*)(ws + 28 * MB);    // 28MB: 4608 x [16][2] f32 = 590KB
  float* out = (float*)d_out;

  prepw_kernel<<<576, 256, 0, stream>>>(Wq, Wk, Wv, wt_img);
  proj_kernel<<<256, 1024, 0, stream>>>(x, wt_img, q_ws, k_img, vt_img);
  attn_kernel<<<1152, 256, 0, stream>>>(q_ws, k_img, vt_img, po, ml, out);
  merge_kernel<<<896, 256, 0, stream>>>(po, ml, out);
}

// Round 11
// 45.571 us; speedup vs baseline: 4.9681x; 1.1046x over previous
//
#include <hip/hip_runtime.h>
#include <hip/hip_bf16.h>

typedef unsigned short u16;
typedef unsigned int u32;
typedef __bf16 bf16;
typedef bf16 bf16x8 __attribute__((ext_vector_type(8)));
typedef float f32x4 __attribute__((ext_vector_type(4)));

#define B_ 8
#define T_ 2048
#define C_ 768
#define MB 1048576ull
#define SCALE_Q 0.1803368867f   /* 0.125 * log2(e): folds 1/sqrt(64) and exp->exp2 */
#define NEG_INF (-__builtin_inff())

#define AS1 __attribute__((address_space(1)))
#define AS3 __attribute__((address_space(3)))

__device__ __forceinline__ void g2l16(const void* g, void* l) {
  __builtin_amdgcn_global_load_lds((AS1 const void*)g, (AS3 void*)l, 16, 0, 0);
}
__device__ __forceinline__ u16 bf2u(bf16 h) {
  union { bf16 h; u16 u; } x; x.h = h; return x.u;
}
#define MFMA16(A, B, C) __builtin_amdgcn_mfma_f32_16x16x32_bf16((A), (B), (C), 0, 0, 0)
#define SBAR() __builtin_amdgcn_sched_barrier(0)
#define BARRIER() do { SBAR(); __builtin_amdgcn_s_barrier(); SBAR(); } while (0)

// ---------------------------------------------------------------------------
// Kernel 1: pre-swizzled Wt image, DOUBLE-STEP packed. (Round-9, unchanged.)
// ---------------------------------------------------------------------------
__global__ __launch_bounds__(256) void prepw_kernel(const float* __restrict__ Wq,
                                                    const float* __restrict__ Wk,
                                                    const float* __restrict__ Wv,
                                                    u16* __restrict__ wt_img) {
  int tid = blockIdx.x * 256 + threadIdx.x;        // 3*768*64 = 147456 exactly
  int jj = tid & 63;
  int k  = (tid >> 6) % C_;
  int m  = tid / (64 * C_);
  const float* W = (m == 0) ? Wq : (m == 1 ? Wk : Wv);
  bf16 hv = (bf16)W[k * 64 + jj];
  int s2 = k >> 6, kk2 = k & 63, j = m * 64 + jj;
  int byteoff = (s2 * 192 + j) * 128 + ((2 * kk2) ^ ((j & 7) << 4));
  *(u16*)((char*)wt_img + byteoff) = bf2u(hv);
}

// ---------------------------------------------------------------------------
// Kernel 2: projections. (Round-9, unchanged — single-variable round.)
// ---------------------------------------------------------------------------
__global__ __launch_bounds__(1024) void proj_kernel(const float* __restrict__ x,
                                                    const u16* __restrict__ wt_img,
                                                    u16* __restrict__ q_ws,
                                                    u16* __restrict__ k_img,
                                                    u16* __restrict__ vt_img) {
  __shared__ __align__(16) char xt[3][16384];
  __shared__ __align__(16) char wt[3][24576];
  int tid = threadIdx.x, lane = tid & 63, w = tid >> 6;
  int wm = w & 3, wn = w >> 2;           // wm: m-tile (16 rows); wn: 48-col band
  int r0 = blockIdx.x * 64;
  int c = lane & 15, g = lane >> 4;

  f32x4 acc[3];
#pragma unroll
  for (int i = 0; i < 3; ++i) acc[i] = (f32x4){0.f, 0.f, 0.f, 0.f};

  int xs = (tid < 512) ? (512 + tid) : (tid - 512);
  int xrow = (xs >> 3) & 63, xch = xs & 7, xhalf = xs >> 9;
  const float* srcx = x + (size_t)(r0 + xrow) * C_ + xhalf * 32 + ((xch ^ (xrow & 7)) << 2);

  auto STAGE = [&](int s, int bs) {
    const char* wsrc = (const char*)wt_img + s * 24576;
    g2l16(wsrc + tid * 16, wt[bs] + tid * 16);
    if (tid < 512) g2l16(wsrc + (1024 + tid) * 16, wt[bs] + (1024 + tid) * 16);
    g2l16(srcx + s * 64, xt[bs] + xs * 16);
  };

  STAGE(0, 0);
  STAGE(1, 1);

  int arow = wm * 16 + c;
  int ax = arow & 7;

  for (int s2 = 0; s2 < 12; ++s2) {
    int cur = s2 % 3;
    if (s2 < 10) {
      STAGE(s2 + 2, (s2 + 2) % 3);
      if (w < 8) asm volatile("s_waitcnt vmcnt(6)" ::: "memory");
      else       asm volatile("s_waitcnt vmcnt(4)" ::: "memory");
    } else if (s2 == 10) {
      if (w < 8) asm volatile("s_waitcnt vmcnt(3)" ::: "memory");
      else       asm volatile("s_waitcnt vmcnt(2)" ::: "memory");
    } else {
      asm volatile("s_waitcnt vmcnt(0)" ::: "memory");
    }
    BARRIER();                           // stage(s2) certified landed
    const char* x0 = xt[cur] + arow * 128;
    const char* x1 = x0 + 8192;
    f32x4 f0 = *(const f32x4*)(x0 + (((2 * g)     ^ ax) << 4));
    f32x4 f1 = *(const f32x4*)(x0 + (((2 * g + 1) ^ ax) << 4));
    f32x4 f2 = *(const f32x4*)(x1 + (((2 * g)     ^ ax) << 4));
    f32x4 f3 = *(const f32x4*)(x1 + (((2 * g + 1) ^ ax) << 4));
    bf16x8 af0, af1;
    af0[0] = (bf16)f0[0]; af0[1] = (bf16)f0[1]; af0[2] = (bf16)f0[2]; af0[3] = (bf16)f0[3];
    af0[4] = (bf16)f1[0]; af0[5] = (bf16)f1[1]; af0[6] = (bf16)f1[2]; af0[7] = (bf16)f1[3];
    af1[0] = (bf16)f2[0]; af1[1] = (bf16)f2[1]; af1[2] = (bf16)f2[2]; af1[3] = (bf16)f2[3];
    af1[4] = (bf16)f3[0]; af1[5] = (bf16)f3[1]; af1[6] = (bf16)f3[2]; af1[7] = (bf16)f3[3];
    const char* bb = wt[cur];
#pragma unroll
    for (int nt = 0; nt < 3; ++nt) {
      int brow = wn * 48 + nt * 16 + c;
      const char* br = bb + brow * 128;
      int bx = (brow & 7) << 4;
      bf16x8 b0 = *(const bf16x8*)(br + ((16 * g) ^ bx));
      bf16x8 b1 = *(const bf16x8*)(br + ((64 + 16 * g) ^ bx));
      acc[nt] = MFMA16(af0, b0, acc[nt]);
      acc[nt] = MFMA16(af1, b1, acc[nt]);
    }
    if (s2 < 11) {
      asm volatile("s_waitcnt lgkmcnt(0)" ::: "memory");
      BARRIER();                         // readers done -> buffer reusable
    }
  }

  // epilogue: D layout col = lane&15, row = (lane>>4)*4 + reg
#pragma unroll
  for (int nt = 0; nt < 3; ++nt) {
    int gc = wn * 48 + nt * 16;
    int m = gc >> 6;
    int h = (gc & 63) + c;
#pragma unroll
    for (int reg = 0; reg < 4; ++reg) {
      int r = r0 + wm * 16 + g * 4 + reg;   // token index
      float val = acc[nt][reg];
      int bb2 = r >> 11, rr = r & 2047, t = rr >> 6;
      if (m == 0) {
        q_ws[(size_t)r * 64 + h] = bf2u((bf16)(val * SCALE_Q));
      } else if (m == 1) {
        int ntk = (rr >> 4) & 3, ck = rr & 15;
        int jp = h >> 5, gg = (h >> 3) & 3, jj = h & 7;
        k_img[((size_t)(bb2 * 32 + t)) * 4096 + ntk * 1024 + jp * 512 + gg * 128 + ck * 8 + jj] = bf2u((bf16)val);
      } else {
        int ht = h >> 4, cv = h & 15;
        int jpv = (rr >> 5) & 1, gv = (rr >> 3) & 3, jv = rr & 7;
        vt_img[((size_t)(bb2 * 32 + t)) * 4096 + ht * 1024 + jpv * 512 + gv * 128 + cv * 8 + jv] = bf2u((bf16)val);
      }
    }
  }
}

// ---------------------------------------------------------------------------
// Kernel 3: causal flash attention, FUSED split-KV + in-LDS merge.
// Block = one (b,qt): 512 thr = 8 waves; wave ci walks tiles [ci*CH, +n),
// CH = ceil(nkt/8) <= 4. K/V per-wave direct register loads from fragment
// images (contiguous 1KB wave transactions); NO barriers in the tile loop.
// Partials (O, m, l) -> padded LDS -> __syncthreads -> in-block weighted
// merge -> out. No po/ml global buffers, no merge kernel, no device fences.
// ---------------------------------------------------------------------------
__device__ __forceinline__ void tile_body2(int t, int t0, int nkt, int q0,
                                           const u16* kbase, const u16* vbase,
                                           const bf16x8& qb0, const bf16x8& qb1,
                                           int c, int g, char* pw,
                                           f32x4 (&accO)[4], float& mrun, float& lrun) {
  // K fragments (B-op rows = kpos), contiguous loads; kf dies after QK^T
  bf16x8 kf[4][2];
#pragma unroll
  for (int nt = 0; nt < 4; ++nt)
#pragma unroll
    for (int jp = 0; jp < 2; ++jp)
      kf[nt][jp] = *(const bf16x8*)(kbase + (size_t)t * 4096 + nt * 1024 + jp * 512);
  SBAR();
  // S^T[kpos][q] = K . Q^T   (rows = kpos, cols = q = lane&15)
  f32x4 st[4];
#pragma unroll
  for (int nt = 0; nt < 4; ++nt) {
    f32x4 z = (f32x4){0.f, 0.f, 0.f, 0.f};
    z = MFMA16(kf[nt][0], qb0, z);
    st[nt] = MFMA16(kf[nt][1], qb1, z);
  }
  // V half 0 (kv slots 0-31) issues while softmax runs
  bf16x8 vf[4];
#pragma unroll
  for (int ht = 0; ht < 4; ++ht)
    vf[ht] = *(const bf16x8*)(vbase + (size_t)t * 4096 + ht * 1024);
  SBAR();
  int tt = t0 + t;
  if (tt == nkt - 1) {   // diagonal tile: mask kpos > q
    int qg = q0 + c, kb2 = tt * 64 + g * 4;
#pragma unroll
    for (int nt = 0; nt < 4; ++nt)
#pragma unroll
      for (int reg = 0; reg < 4; ++reg)
        if (kb2 + nt * 16 + reg > qg) st[nt][reg] = NEG_INF;
  }
  // lane-local softmax over 16 held kpos + cross-group (xor16, xor32)
  float smax = st[0][0];
#pragma unroll
  for (int nt = 0; nt < 4; ++nt)
#pragma unroll
    for (int reg = 0; reg < 4; ++reg) smax = fmaxf(smax, st[nt][reg]);
  smax = fmaxf(smax, __shfl_xor(smax, 16));
  smax = fmaxf(smax, __shfl_xor(smax, 32));
  float mnew = fmaxf(mrun, smax);
  float sf = exp2f(mrun - mnew);
  float rsum = 0.f;
  u32 pk[4][2];
#pragma unroll
  for (int nt = 0; nt < 4; ++nt)
#pragma unroll
    for (int jp = 0; jp < 2; ++jp) {
      float p0 = exp2f(st[nt][2 * jp] - mnew);
      float p1 = exp2f(st[nt][2 * jp + 1] - mnew);
      rsum += p0 + p1;
      pk[nt][jp] = (u32)bf2u((bf16)p0) | ((u32)bf2u((bf16)p1) << 16);
    }
  rsum += __shfl_xor(rsum, 16);
  rsum += __shfl_xor(rsum, 32);
  lrun = lrun * sf + rsum;
  mrun = mnew;
#pragma unroll
  for (int ht = 0; ht < 4; ++ht) accO[ht] *= sf;
  // P (q-row c, 64 kpos) -> wave-private swizzled LDS row, packed b32 writes
  int swz = (c & 7) << 4;
#pragma unroll
  for (int nt = 0; nt < 4; ++nt)
#pragma unroll
    for (int jp = 0; jp < 2; ++jp) {
      int kpos = nt * 16 + g * 4 + 2 * jp;
      *(u32*)(pw + ((2 * kpos) ^ swz)) = pk[nt][jp];
    }
  // PV half 0
  bf16x8 pf0 = *(const bf16x8*)(pw + ((16 * g) ^ swz));
#pragma unroll
  for (int ht = 0; ht < 4; ++ht)
    accO[ht] = MFMA16(vf[ht], pf0, accO[ht]);
  // V half 1 (kv slots 32-63), PV half 1
#pragma unroll
  for (int ht = 0; ht < 4; ++ht)
    vf[ht] = *(const bf16x8*)(vbase + (size_t)t * 4096 + ht * 1024 + 512);
  SBAR();
  bf16x8 pf1 = *(const bf16x8*)(pw + ((64 + 16 * g) ^ swz));
#pragma unroll
  for (int ht = 0; ht < 4; ++ht)
    accO[ht] = MFMA16(vf[ht], pf1, accO[ht]);
}

__global__ __launch_bounds__(512, 4) void attn_kernel(const u16* __restrict__ q_ws,
                                                      const u16* __restrict__ k_img,
                                                      const u16* __restrict__ vt_img,
                                                      float* __restrict__ out) {
  __shared__ __align__(16) char sP[8 * 2048];       // wave-private P tiles
  __shared__ float po_s[8][64][17];                 // padded: conflict-free both ways
  __shared__ float2 ml_s[8][16];
  int tid = threadIdx.x, lane = tid & 63, w = tid >> 6;
  int bid = blockIdx.x;
  int b = bid & 7;                       // batch -> XCD
  int qt = bid >> 3;                     // [0, 128)
  int nkt = (qt >> 2) + 1;               // 1..32 KV tiles
  int CH = (nkt + 7) >> 3;               // 1..4 tiles per wave
  int t0 = w * CH;
  int n = nkt - t0; if (n < 0) n = 0; if (n > CH) n = CH;
  int q0 = qt * 16;
  int c = lane & 15, g = lane >> 4;

  // Q as B-operand: col = q = c, k(h) = 8g+j; q pre-scaled by 0.125*log2e
  const u16* qb_p = q_ws + ((size_t)b * T_ + q0 + c) * 64 + 8 * g;
  bf16x8 qb0 = *(const bf16x8*)qb_p;
  bf16x8 qb1 = *(const bf16x8*)(qb_p + 32);

  const u16* kbase = k_img + ((size_t)(b * 32 + t0)) * 4096 + lane * 8;
  const u16* vbase = vt_img + ((size_t)(b * 32 + t0)) * 4096 + lane * 8;

  f32x4 accO[4];
#pragma unroll
  for (int i = 0; i < 4; ++i) accO[i] = (f32x4){0.f, 0.f, 0.f, 0.f};
  float mrun = NEG_INF, lrun = 0.f;
  char* pw = sP + w * 2048 + c * 128;

  if (n > 0) tile_body2(0, t0, nkt, q0, kbase, vbase, qb0, qb1, c, g, pw, accO, mrun, lrun);
  if (n > 1) tile_body2(1, t0, nkt, q0, kbase, vbase, qb0, qb1, c, g, pw, accO, mrun, lrun);
  if (n > 2) tile_body2(2, t0, nkt, q0, kbase, vbase, qb0, qb1, c, g, pw, accO, mrun, lrun);
  if (n > 3) tile_body2(3, t0, nkt, q0, kbase, vbase, qb0, qb1, c, g, pw, accO, mrun, lrun);

  // publish partials to LDS (active waves only)
  if (n > 0) {
#pragma unroll
    for (int ht = 0; ht < 4; ++ht)
#pragma unroll
      for (int reg = 0; reg < 4; ++reg)
        po_s[w][ht * 16 + g * 4 + reg][c] = accO[ht][reg];
    if (g == 0) ml_s[w][c] = make_float2(mrun, lrun);
  }
  __syncthreads();

  // in-block merge: wave w handles q-rows {w, w+8}; lane holds h = lane.
  int nact = (nkt + CH - 1) / CH;        // number of active chunk waves
#pragma unroll
  for (int half = 0; half < 2; ++half) {
    int qq = w + half * 8;
    float M = NEG_INF;
#pragma unroll
    for (int ci = 0; ci < 8; ++ci)
      if (ci < nact) M = fmaxf(M, ml_s[ci][qq].x);
    float L = 0.f, s = 0.f;
#pragma unroll
    for (int ci = 0; ci < 8; ++ci)
      if (ci < nact) {
        float2 mlv = ml_s[ci][qq];
        float wg = exp2f(mlv.x - M);
        L += wg * mlv.y;
        s += wg * po_s[ci][lane][qq];
      }
    out[((size_t)b * T_ + q0 + qq) * 64 + lane] = s / L;
  }
}

// ---------------------------------------------------------------------------
extern "C" void kernel_launch(void* const* d_in, const int* in_sizes, int n_in,
                              void* d_out, int out_size, void* d_ws, size_t ws_size,
                              hipStream_t stream) {
  const float* x  = (const float*)d_in[0];
  const float* Wk = (const float*)d_in[1];
  const float* Wq = (const float*)d_in[2];
  const float* Wv = (const float*)d_in[3];
  char* ws = (char*)d_ws;
  u16* q_ws   = (u16*)(ws);                //  0MB: [16384][64] bf16 (q * 0.125*log2e)
  u16* k_img  = (u16*)(ws + 2 * MB);       //  2MB: [8][32][4096] u16 tile image
  u16* vt_img = (u16*)(ws + 4 * MB);       //  4MB: [8][32][4096] u16 tile image
  u16* wt_img = (u16*)(ws + 6 * MB);       //  6MB: 295KB packed swizzled weights
  float* out = (float*)d_out;

  prepw_kernel<<<576, 256, 0, stream>>>(Wq, Wk, Wv, wt_img);
  proj_kernel<<<256, 1024, 0, stream>>>(x, wt_img, q_ws, k_img, vt_img);
  attn_kernel<<<1024, 512, 0, stream>>>(q_ws, k_img, vt_img, out);
}